// Round 1
// baseline (1235.469 us; speedup 1.0000x reference)
//
#include <hip/hip_runtime.h>

// Problem constants (derived from in_sizes at launch, for reference):
//   N_NODES=100000, N_EDGES=800000, D_EDGE=64, D_NODE=128, D_IN=256, D_OUT=128
//
// Strategy change vs previous version:
//   The fp32 scatter-atomics were atomic-path-bound (WRITE_SIZE == 256B/edge,
//   23% HBM, 7% VALU). Replace scatter with CSR-build (int atomics on a 400KB
//   histogram, chunked scan, permute) + register-accumulating GATHER fused
//   directly into the GEMM's LDS staging. No float atomics, no agg buffers,
//   no 51MB memset.

#define NB 32          // nodes per block in fused kernel (100000 % 32 == 0 -> 3125 blocks)
#define CHUNK 512      // scan chunk size
#define NCHUNK_MAX 256 // max chunks supported by single-block partial scan (n_nodes <= 131072)

// ---------------------------------------------------------------------------
// 1) Histogram: counts_x[recv[e]]++  (int atomics, 400KB target, cheap)
// ---------------------------------------------------------------------------
__global__ __launch_bounds__(256) void hist_kernel(
    const int* __restrict__ ra, const int* __restrict__ rb,
    int* __restrict__ counts_a, int* __restrict__ counts_b, int n_edges) {
  const int e = blockIdx.x * 256 + threadIdx.x;
  if (e < n_edges) {
    atomicAdd(&counts_a[ra[e]], 1);
    atomicAdd(&counts_b[rb[e]], 1);
  }
}

// ---------------------------------------------------------------------------
// 2) Per-chunk inclusive scan of counts (Hillis-Steele over CHUNK in LDS).
//    blockIdx.y selects array (0=a, 1=b). Writes inclusive scan + chunk total.
// ---------------------------------------------------------------------------
__global__ __launch_bounds__(CHUNK) void scan_chunks(
    const int* __restrict__ counts, int* __restrict__ incl,
    int* __restrict__ partials, int apad) {
  __shared__ int sh[2][CHUNK];
  const int base = blockIdx.y * apad;
  const int i = blockIdx.x * CHUNK + threadIdx.x;
  const int t = threadIdx.x;
  sh[0][t] = counts[base + i];
  __syncthreads();
  int src = 0;
  for (int off = 1; off < CHUNK; off <<= 1) {
    int v = sh[src][t];
    if (t >= off) v += sh[src][t - off];
    sh[src ^ 1][t] = v;
    src ^= 1;
    __syncthreads();
  }
  const int inc = sh[src][t];
  incl[base + i] = inc;
  if (t == CHUNK - 1) partials[blockIdx.y * NCHUNK_MAX + blockIdx.x] = inc;
}

// ---------------------------------------------------------------------------
// 3) Scan chunk totals (single block per array) -> exclusive chunk offsets.
// ---------------------------------------------------------------------------
__global__ __launch_bounds__(NCHUNK_MAX) void scan_partials(
    int* __restrict__ partials, int n_chunks) {
  __shared__ int sh[2][NCHUNK_MAX];
  const int base = blockIdx.y * NCHUNK_MAX;
  const int t = threadIdx.x;
  const int own = (t < n_chunks) ? partials[base + t] : 0;
  sh[0][t] = own;
  __syncthreads();
  int src = 0;
  for (int off = 1; off < NCHUNK_MAX; off <<= 1) {
    int v = sh[src][t];
    if (t >= off) v += sh[src][t - off];
    sh[src ^ 1][t] = v;
    src ^= 1;
    __syncthreads();
  }
  if (t < n_chunks) partials[base + t] = sh[src][t] - own;  // exclusive
}

// ---------------------------------------------------------------------------
// 4) Finalize: cursor[i] = exclusive global offset = incl[i] - counts[i] + chunk_off
//    (in-place on the incl array)
// ---------------------------------------------------------------------------
__global__ __launch_bounds__(CHUNK) void finalize_offsets(
    const int* __restrict__ counts, int* __restrict__ cursor,
    const int* __restrict__ partials, int apad) {
  const int base = blockIdx.y * apad;
  const int i = blockIdx.x * CHUNK + threadIdx.x;
  cursor[base + i] = cursor[base + i] - counts[base + i] +
                     partials[blockIdx.y * NCHUNK_MAX + blockIdx.x];
}

// ---------------------------------------------------------------------------
// 5) Permute: bucket edge ids by receiver. After this, cursor[n] == bucket END.
// ---------------------------------------------------------------------------
__global__ __launch_bounds__(256) void permute_kernel(
    const int* __restrict__ ra, const int* __restrict__ rb,
    int* __restrict__ cur_a, int* __restrict__ cur_b,
    int* __restrict__ eid_a, int* __restrict__ eid_b, int n_edges) {
  const int e = blockIdx.x * 256 + threadIdx.x;
  if (e < n_edges) {
    const int pa = atomicAdd(&cur_a[ra[e]], 1);
    eid_a[pa] = e;
    const int pb = atomicAdd(&cur_b[rb[e]], 1);
    eid_b[pb] = e;
  }
}

// ---------------------------------------------------------------------------
// 6) Fused gather + concat + GEMM + bias:
//   out[n,:] = [sum_{e->n} edata_a[e] | sum_{e->n} edata_b[e] | vdata[n]] @ W + b
// Block = 256 threads / 4 waves, NB=32 nodes. Each wave gathers 8 nodes'
// edge rows (lane = feature, 256B coalesced per edge) accumulating in
// registers, writes xs rows once; vdata staged as before. GEMM loop is the
// proven version from the previous kernel (stride 260, broadcast LDS reads).
// ---------------------------------------------------------------------------
__device__ __forceinline__ void fma4(float4& acc, float s, const float4& w) {
  acc.x = fmaf(s, w.x, acc.x);
  acc.y = fmaf(s, w.y, acc.y);
  acc.z = fmaf(s, w.z, acc.z);
  acc.w = fmaf(s, w.w, acc.w);
}

__global__ __launch_bounds__(256) void fused_gather_gemm(
    const float* __restrict__ edata_a, const float* __restrict__ edata_b,
    const int* __restrict__ eid_a, const int* __restrict__ eid_b,
    const int* __restrict__ end_a, const int* __restrict__ cnt_a,
    const int* __restrict__ end_b, const int* __restrict__ cnt_b,
    const float* __restrict__ vdata, const float* __restrict__ W,
    const float* __restrict__ bias, float* __restrict__ out, int n_nodes) {
  __shared__ float xs[NB][260];

  const int tid = threadIdx.x;
  const int lane = tid & 63;
  const int wv = tid >> 6;  // wave 0..3
  const int n0 = blockIdx.x * NB;

  // ---- stage vdata into cols 128..255 (independent of gather; issues early) ----
  const float4* V4 = (const float4*)(vdata + (size_t)n0 * 128);
#pragma unroll
  for (int i = tid; i < NB * 32; i += 256) {
    const int node = i >> 5;
    const int kk = (i & 31) << 2;
    *(float4*)&xs[node][128 + kk] = V4[i];
  }

  // ---- gather agg_a / agg_b into cols 0..127: wave wv owns nodes wv*8..wv*8+7 ----
  for (int j = 0; j < 8; ++j) {
    const int ln = wv * 8 + j;
    const int n = n0 + ln;
    float sa = 0.f, sb = 0.f;
    if (n < n_nodes) {
      const int ea = end_a[n], ca = cnt_a[n];
      const int eb = end_b[n], cb = cnt_b[n];
      const int ia = ea - ca, ib = eb - cb;
      const int m = ca > cb ? ca : cb;
      for (int t = 0; t < m; ++t) {  // two independent chains (a,b) for MLP
        if (t < ca) sa += edata_a[(size_t)eid_a[ia + t] * 64 + lane];
        if (t < cb) sb += edata_b[(size_t)eid_b[ib + t] * 64 + lane];
      }
    }
    xs[ln][lane] = sa;       // 64 consecutive floats: conflict-free
    xs[ln][64 + lane] = sb;
  }
  __syncthreads();

  // ---- GEMM: thread t -> cols 4*(t&31)..+3, nodes (t>>5)*4..+3 ----
  const int c = tid & 31;
  const int nset = tid >> 5;
  const float4* W4 = (const float4*)W;

  float4 acc0 = {0.f, 0.f, 0.f, 0.f};
  float4 acc1 = acc0, acc2 = acc0, acc3 = acc0;

#pragma unroll 4
  for (int k = 0; k < 256; k += 4) {
    const float4 w0 = W4[(k + 0) * 32 + c];
    const float4 w1 = W4[(k + 1) * 32 + c];
    const float4 w2 = W4[(k + 2) * 32 + c];
    const float4 w3 = W4[(k + 3) * 32 + c];
    const float4 x0 = *(const float4*)&xs[nset * 4 + 0][k];
    const float4 x1 = *(const float4*)&xs[nset * 4 + 1][k];
    const float4 x2 = *(const float4*)&xs[nset * 4 + 2][k];
    const float4 x3 = *(const float4*)&xs[nset * 4 + 3][k];

    fma4(acc0, x0.x, w0); fma4(acc0, x0.y, w1); fma4(acc0, x0.z, w2); fma4(acc0, x0.w, w3);
    fma4(acc1, x1.x, w0); fma4(acc1, x1.y, w1); fma4(acc1, x1.z, w2); fma4(acc1, x1.w, w3);
    fma4(acc2, x2.x, w0); fma4(acc2, x2.y, w1); fma4(acc2, x2.z, w2); fma4(acc2, x2.w, w3);
    fma4(acc3, x3.x, w0); fma4(acc3, x3.y, w1); fma4(acc3, x3.z, w2); fma4(acc3, x3.w, w3);
  }

  // ---- epilogue: bias + store ----
  const float4 bb = ((const float4*)bias)[c];
  acc0.x += bb.x; acc0.y += bb.y; acc0.z += bb.z; acc0.w += bb.w;
  acc1.x += bb.x; acc1.y += bb.y; acc1.z += bb.z; acc1.w += bb.w;
  acc2.x += bb.x; acc2.y += bb.y; acc2.z += bb.z; acc2.w += bb.w;
  acc3.x += bb.x; acc3.y += bb.y; acc3.z += bb.z; acc3.w += bb.w;

  float4* O4 = (float4*)out;
  const int nb = n0 + nset * 4;
  if (nb + 3 < n_nodes) {
    O4[(size_t)(nb + 0) * 32 + c] = acc0;
    O4[(size_t)(nb + 1) * 32 + c] = acc1;
    O4[(size_t)(nb + 2) * 32 + c] = acc2;
    O4[(size_t)(nb + 3) * 32 + c] = acc3;
  } else {
    if (nb + 0 < n_nodes) O4[(size_t)(nb + 0) * 32 + c] = acc0;
    if (nb + 1 < n_nodes) O4[(size_t)(nb + 1) * 32 + c] = acc1;
    if (nb + 2 < n_nodes) O4[(size_t)(nb + 2) * 32 + c] = acc2;
    if (nb + 3 < n_nodes) O4[(size_t)(nb + 3) * 32 + c] = acc3;
  }
}

// ---------------------------------------------------------------------------
// Launch
// ---------------------------------------------------------------------------
extern "C" void kernel_launch(void* const* d_in, const int* in_sizes, int n_in,
                              void* d_out, int out_size, void* d_ws, size_t ws_size,
                              hipStream_t stream) {
  const float* vdata   = (const float*)d_in[0];
  const float* edata_a = (const float*)d_in[1];
  const float* edata_b = (const float*)d_in[2];
  const int*   conn_a  = (const int*)d_in[3];  // [2, E] int32 (JAX canonicalizes int64->int32)
  const int*   conn_b  = (const int*)d_in[4];
  const float* W       = (const float*)d_in[5];
  const float* bias    = (const float*)d_in[6];
  float*       out     = (float*)d_out;

  const int n_nodes = in_sizes[0] / 128;  // 100000
  const int n_edges = in_sizes[1] / 64;   // 800000

  const int* recv_a = conn_a + n_edges;   // row 1 = receivers
  const int* recv_b = conn_b + n_edges;

  const int nchunks = (n_nodes + CHUNK - 1) / CHUNK;  // 196
  const int apad = nchunks * CHUNK;                   // 100352

  // Workspace layout (ints), ~8 MB total (ws poisoned each call -> everything
  // below is either memset or fully overwritten before being read):
  int* counts   = (int*)d_ws;                 // 2*apad   (a then b)
  int* cursor   = counts + 2 * (size_t)apad;  // 2*apad   (incl scan -> excl cursor -> bucket end)
  int* partials = cursor + 2 * (size_t)apad;  // 2*NCHUNK_MAX
  int* eid      = partials + 2 * NCHUNK_MAX;  // 2*n_edges
  int* counts_a = counts;
  int* counts_b = counts + apad;
  int* cur_a    = cursor;
  int* cur_b    = cursor + apad;
  int* eid_a    = eid;
  int* eid_b    = eid + n_edges;

  hipMemsetAsync(counts, 0, (size_t)2 * apad * sizeof(int), stream);

  const int eblocks = (n_edges + 255) / 256;  // 3125
  hist_kernel<<<eblocks, 256, 0, stream>>>(recv_a, recv_b, counts_a, counts_b, n_edges);
  scan_chunks<<<dim3(nchunks, 2), CHUNK, 0, stream>>>(counts, cursor, partials, apad);
  scan_partials<<<dim3(1, 2), NCHUNK_MAX, 0, stream>>>(partials, nchunks);
  finalize_offsets<<<dim3(nchunks, 2), CHUNK, 0, stream>>>(counts, cursor, partials, apad);
  permute_kernel<<<eblocks, 256, 0, stream>>>(recv_a, recv_b, cur_a, cur_b, eid_a, eid_b, n_edges);

  const int gblocks = (n_nodes + NB - 1) / NB;  // 3125
  fused_gather_gemm<<<gblocks, 256, 0, stream>>>(
      edata_a, edata_b, eid_a, eid_b, cur_a, counts_a, cur_b, counts_b,
      vdata, W, bias, out, n_nodes);
}

// Round 2
// 774.767 us; speedup vs baseline: 1.5946x; 1.5946x over previous
//
#include <hip/hip_runtime.h>

// Problem constants (derived from in_sizes at launch, for reference):
//   N_NODES=100000, N_EDGES=800000, D_EDGE=64, D_NODE=128, D_IN=256, D_OUT=128
//
// Round-2 change: the CSR gather in the fused kernel was a serial
// dependent-load chain (eid load -> edata load per edge, MLP~1, 395 GB/s,
// 10% VALU). Restructure for MLP~16: lane-parallel eid prefetch (one vector
// load per node covers 64 edges), then strip-mine the 8 nodes of each wave in
// lockstep so every iteration issues 16 independent predicated edata row
// loads. Metadata hoisted to SGPRs via readlane. CSR build unchanged.

#define NB 32          // nodes per block in fused kernel (100000 % 32 == 0 -> 3125 blocks)
#define CHUNK 512      // scan chunk size
#define NCHUNK_MAX 256 // max chunks supported by single-block partial scan (n_nodes <= 131072)

// ---------------------------------------------------------------------------
// 1) Histogram: counts_x[recv[e]]++  (int atomics on L2-resident 400KB, cheap)
// ---------------------------------------------------------------------------
__global__ __launch_bounds__(256) void hist_kernel(
    const int* __restrict__ ra, const int* __restrict__ rb,
    int* __restrict__ counts_a, int* __restrict__ counts_b, int n_edges) {
  const int e = blockIdx.x * 256 + threadIdx.x;
  if (e < n_edges) {
    atomicAdd(&counts_a[ra[e]], 1);
    atomicAdd(&counts_b[rb[e]], 1);
  }
}

// ---------------------------------------------------------------------------
// 2) Per-chunk inclusive scan of counts (Hillis-Steele over CHUNK in LDS).
// ---------------------------------------------------------------------------
__global__ __launch_bounds__(CHUNK) void scan_chunks(
    const int* __restrict__ counts, int* __restrict__ incl,
    int* __restrict__ partials, int apad) {
  __shared__ int sh[2][CHUNK];
  const int base = blockIdx.y * apad;
  const int i = blockIdx.x * CHUNK + threadIdx.x;
  const int t = threadIdx.x;
  sh[0][t] = counts[base + i];
  __syncthreads();
  int src = 0;
  for (int off = 1; off < CHUNK; off <<= 1) {
    int v = sh[src][t];
    if (t >= off) v += sh[src][t - off];
    sh[src ^ 1][t] = v;
    src ^= 1;
    __syncthreads();
  }
  const int inc = sh[src][t];
  incl[base + i] = inc;
  if (t == CHUNK - 1) partials[blockIdx.y * NCHUNK_MAX + blockIdx.x] = inc;
}

// ---------------------------------------------------------------------------
// 3) Scan chunk totals (single block per array) -> exclusive chunk offsets.
// ---------------------------------------------------------------------------
__global__ __launch_bounds__(NCHUNK_MAX) void scan_partials(
    int* __restrict__ partials, int n_chunks) {
  __shared__ int sh[2][NCHUNK_MAX];
  const int base = blockIdx.y * NCHUNK_MAX;
  const int t = threadIdx.x;
  const int own = (t < n_chunks) ? partials[base + t] : 0;
  sh[0][t] = own;
  __syncthreads();
  int src = 0;
  for (int off = 1; off < NCHUNK_MAX; off <<= 1) {
    int v = sh[src][t];
    if (t >= off) v += sh[src][t - off];
    sh[src ^ 1][t] = v;
    src ^= 1;
    __syncthreads();
  }
  if (t < n_chunks) partials[base + t] = sh[src][t] - own;  // exclusive
}

// ---------------------------------------------------------------------------
// 4) Finalize: cursor[i] = incl[i] - counts[i] + chunk_off  (exclusive offset)
// ---------------------------------------------------------------------------
__global__ __launch_bounds__(CHUNK) void finalize_offsets(
    const int* __restrict__ counts, int* __restrict__ cursor,
    const int* __restrict__ partials, int apad) {
  const int base = blockIdx.y * apad;
  const int i = blockIdx.x * CHUNK + threadIdx.x;
  cursor[base + i] = cursor[base + i] - counts[base + i] +
                     partials[blockIdx.y * NCHUNK_MAX + blockIdx.x];
}

// ---------------------------------------------------------------------------
// 5) Permute: bucket edge ids by receiver. After this, cursor[n] == bucket END.
// ---------------------------------------------------------------------------
__global__ __launch_bounds__(256) void permute_kernel(
    const int* __restrict__ ra, const int* __restrict__ rb,
    int* __restrict__ cur_a, int* __restrict__ cur_b,
    int* __restrict__ eid_a, int* __restrict__ eid_b, int n_edges) {
  const int e = blockIdx.x * 256 + threadIdx.x;
  if (e < n_edges) {
    const int pa = atomicAdd(&cur_a[ra[e]], 1);
    eid_a[pa] = e;
    const int pb = atomicAdd(&cur_b[rb[e]], 1);
    eid_b[pb] = e;
  }
}

// ---------------------------------------------------------------------------
// 6) Fused gather + concat + GEMM + bias.
//   Gather (per wave, 8 nodes): lane-parallel eid prefetch, then lockstep
//   strip-mine over edge index t issuing 16 independent predicated row loads
//   per iteration. lane = feature.
// ---------------------------------------------------------------------------
__device__ __forceinline__ void fma4(float4& acc, float s, const float4& w) {
  acc.x = fmaf(s, w.x, acc.x);
  acc.y = fmaf(s, w.y, acc.y);
  acc.z = fmaf(s, w.z, acc.z);
  acc.w = fmaf(s, w.w, acc.w);
}

__global__ __launch_bounds__(256) void fused_gather_gemm(
    const float* __restrict__ edata_a, const float* __restrict__ edata_b,
    const int* __restrict__ eid_a, const int* __restrict__ eid_b,
    const int* __restrict__ end_a, const int* __restrict__ cnt_a,
    const int* __restrict__ end_b, const int* __restrict__ cnt_b,
    const float* __restrict__ vdata, const float* __restrict__ W,
    const float* __restrict__ bias, float* __restrict__ out, int n_nodes) {
  __shared__ float xs[NB][260];

  const int tid = threadIdx.x;
  const int lane = tid & 63;
  const int wv = tid >> 6;   // wave 0..3
  const int n0 = blockIdx.x * NB;
  const int ln0 = wv * 8;    // this wave's first local node

  // ---- metadata: lane&7 -> node j (8 distinct addresses, redundant lanes ok)
  const int nj = n0 + ln0 + (lane & 7);
  int ea = 0, ca = 0, eb = 0, cb = 0;
  if (nj < n_nodes) {
    ea = end_a[nj]; ca = cnt_a[nj];
    eb = end_b[nj]; cb = cnt_b[nj];
  }
  const int ia = ea - ca, ib = eb - cb;

  // hoist per-node metadata to SGPRs (wave-uniform)
  int caj[8], iaj[8], cbj[8], ibj[8];
#pragma unroll
  for (int j = 0; j < 8; ++j) {
    caj[j] = __builtin_amdgcn_readlane(ca, j);
    iaj[j] = __builtin_amdgcn_readlane(ia, j);
    cbj[j] = __builtin_amdgcn_readlane(cb, j);
    ibj[j] = __builtin_amdgcn_readlane(ib, j);
  }

  // ---- lane-parallel eid prefetch: lane t holds edge-id t of node j
  int eA[8], eB[8];
#pragma unroll
  for (int j = 0; j < 8; ++j) {
    eA[j] = (lane < caj[j]) ? eid_a[iaj[j] + lane] : 0;
    eB[j] = (lane < cbj[j]) ? eid_b[ibj[j] + lane] : 0;
  }

  // ---- stage vdata into cols 128..255 (independent VMEM; fills latency) ----
  const float4* V4 = (const float4*)(vdata + (size_t)n0 * 128);
#pragma unroll
  for (int i = tid; i < NB * 32; i += 256) {
    const int node = i >> 5;
    const int kk = (i & 31) << 2;
    *(float4*)&xs[node][128 + kk] = V4[i];
  }

  // ---- lockstep accumulation: per t, 16 independent predicated row loads ----
  float sa[8] = {0.f, 0.f, 0.f, 0.f, 0.f, 0.f, 0.f, 0.f};
  float sb[8] = {0.f, 0.f, 0.f, 0.f, 0.f, 0.f, 0.f, 0.f};
  int mdeg = 0;
#pragma unroll
  for (int j = 0; j < 8; ++j) {
    const int mj = caj[j] > cbj[j] ? caj[j] : cbj[j];
    mdeg = mdeg > mj ? mdeg : mj;
  }
  const int mmain = mdeg < 64 ? mdeg : 64;
  for (int t = 0; t < mmain; ++t) {
#pragma unroll
    for (int j = 0; j < 8; ++j) {
      const int ra = __shfl(eA[j], t);
      const int rb = __shfl(eB[j], t);
      const bool pa = t < caj[j];
      const bool pb = t < cbj[j];
      const float va = edata_a[(size_t)(pa ? ra : 0) * 64 + lane];
      const float vb = edata_b[(size_t)(pb ? rb : 0) * 64 + lane];
      sa[j] += pa ? va : 0.f;
      sb[j] += pb ? vb : 0.f;
    }
  }
  // rare tail: node degree > 64 (slow serial path, keeps same FP sum order)
  if (mdeg > 64) {
#pragma unroll 1
    for (int j = 0; j < 8; ++j) {
      for (int t = 64; t < caj[j]; ++t)
        sa[j] += edata_a[(size_t)eid_a[iaj[j] + t] * 64 + lane];
      for (int t = 64; t < cbj[j]; ++t)
        sb[j] += edata_b[(size_t)eid_b[ibj[j] + t] * 64 + lane];
    }
  }

#pragma unroll
  for (int j = 0; j < 8; ++j) {
    xs[ln0 + j][lane] = sa[j];        // 64 consecutive floats: conflict-free
    xs[ln0 + j][64 + lane] = sb[j];
  }
  __syncthreads();

  // ---- GEMM: thread t -> cols 4*(t&31)..+3, nodes (t>>5)*4..+3 ----
  const int c = tid & 31;
  const int nset = tid >> 5;
  const float4* W4 = (const float4*)W;

  float4 acc0 = {0.f, 0.f, 0.f, 0.f};
  float4 acc1 = acc0, acc2 = acc0, acc3 = acc0;

#pragma unroll 4
  for (int k = 0; k < 256; k += 4) {
    const float4 w0 = W4[(k + 0) * 32 + c];
    const float4 w1 = W4[(k + 1) * 32 + c];
    const float4 w2 = W4[(k + 2) * 32 + c];
    const float4 w3 = W4[(k + 3) * 32 + c];
    const float4 x0 = *(const float4*)&xs[nset * 4 + 0][k];
    const float4 x1 = *(const float4*)&xs[nset * 4 + 1][k];
    const float4 x2 = *(const float4*)&xs[nset * 4 + 2][k];
    const float4 x3 = *(const float4*)&xs[nset * 4 + 3][k];

    fma4(acc0, x0.x, w0); fma4(acc0, x0.y, w1); fma4(acc0, x0.z, w2); fma4(acc0, x0.w, w3);
    fma4(acc1, x1.x, w0); fma4(acc1, x1.y, w1); fma4(acc1, x1.z, w2); fma4(acc1, x1.w, w3);
    fma4(acc2, x2.x, w0); fma4(acc2, x2.y, w1); fma4(acc2, x2.z, w2); fma4(acc2, x2.w, w3);
    fma4(acc3, x3.x, w0); fma4(acc3, x3.y, w1); fma4(acc3, x3.z, w2); fma4(acc3, x3.w, w3);
  }

  // ---- epilogue: bias + store ----
  const float4 bb = ((const float4*)bias)[c];
  acc0.x += bb.x; acc0.y += bb.y; acc0.z += bb.z; acc0.w += bb.w;
  acc1.x += bb.x; acc1.y += bb.y; acc1.z += bb.z; acc1.w += bb.w;
  acc2.x += bb.x; acc2.y += bb.y; acc2.z += bb.z; acc2.w += bb.w;
  acc3.x += bb.x; acc3.y += bb.y; acc3.z += bb.z; acc3.w += bb.w;

  float4* O4 = (float4*)out;
  const int nb = n0 + nset * 4;
  if (nb + 3 < n_nodes) {
    O4[(size_t)(nb + 0) * 32 + c] = acc0;
    O4[(size_t)(nb + 1) * 32 + c] = acc1;
    O4[(size_t)(nb + 2) * 32 + c] = acc2;
    O4[(size_t)(nb + 3) * 32 + c] = acc3;
  } else {
    if (nb + 0 < n_nodes) O4[(size_t)(nb + 0) * 32 + c] = acc0;
    if (nb + 1 < n_nodes) O4[(size_t)(nb + 1) * 32 + c] = acc1;
    if (nb + 2 < n_nodes) O4[(size_t)(nb + 2) * 32 + c] = acc2;
    if (nb + 3 < n_nodes) O4[(size_t)(nb + 3) * 32 + c] = acc3;
  }
}

// ---------------------------------------------------------------------------
// Launch
// ---------------------------------------------------------------------------
extern "C" void kernel_launch(void* const* d_in, const int* in_sizes, int n_in,
                              void* d_out, int out_size, void* d_ws, size_t ws_size,
                              hipStream_t stream) {
  const float* vdata   = (const float*)d_in[0];
  const float* edata_a = (const float*)d_in[1];
  const float* edata_b = (const float*)d_in[2];
  const int*   conn_a  = (const int*)d_in[3];  // [2, E] int32 (JAX canonicalizes int64->int32)
  const int*   conn_b  = (const int*)d_in[4];
  const float* W       = (const float*)d_in[5];
  const float* bias    = (const float*)d_in[6];
  float*       out     = (float*)d_out;

  const int n_nodes = in_sizes[0] / 128;  // 100000
  const int n_edges = in_sizes[1] / 64;   // 800000

  const int* recv_a = conn_a + n_edges;   // row 1 = receivers
  const int* recv_b = conn_b + n_edges;

  const int nchunks = (n_nodes + CHUNK - 1) / CHUNK;  // 196
  const int apad = nchunks * CHUNK;                   // 100352

  // Workspace layout (ints), ~8 MB total:
  int* counts   = (int*)d_ws;                 // 2*apad   (a then b)
  int* cursor   = counts + 2 * (size_t)apad;  // 2*apad   (incl scan -> excl cursor -> bucket end)
  int* partials = cursor + 2 * (size_t)apad;  // 2*NCHUNK_MAX
  int* eid      = partials + 2 * NCHUNK_MAX;  // 2*n_edges
  int* counts_a = counts;
  int* counts_b = counts + apad;
  int* cur_a    = cursor;
  int* cur_b    = cursor + apad;
  int* eid_a    = eid;
  int* eid_b    = eid + n_edges;

  hipMemsetAsync(counts, 0, (size_t)2 * apad * sizeof(int), stream);

  const int eblocks = (n_edges + 255) / 256;  // 3125
  hist_kernel<<<eblocks, 256, 0, stream>>>(recv_a, recv_b, counts_a, counts_b, n_edges);
  scan_chunks<<<dim3(nchunks, 2), CHUNK, 0, stream>>>(counts, cursor, partials, apad);
  scan_partials<<<dim3(1, 2), NCHUNK_MAX, 0, stream>>>(partials, nchunks);
  finalize_offsets<<<dim3(nchunks, 2), CHUNK, 0, stream>>>(counts, cursor, partials, apad);
  permute_kernel<<<eblocks, 256, 0, stream>>>(recv_a, recv_b, cur_a, cur_b, eid_a, eid_b, n_edges);

  const int gblocks = (n_nodes + NB - 1) / NB;  // 3125
  fused_gather_gemm<<<gblocks, 256, 0, stream>>>(
      edata_a, edata_b, eid_a, eid_b, cur_a, counts_a, cur_b, counts_b,
      vdata, W, bias, out, n_nodes);
}

// Round 3
// 749.633 us; speedup vs baseline: 1.6481x; 1.0335x over previous
//
#include <hip/hip_runtime.h>

// Problem constants: N_NODES=100000, N_EDGES=800000, D_EDGE=64, D_NODE=128,
//                    D_IN=256, D_OUT=128
//
// Round-3 changes:
//  (a) Gather processes 4 edges per load instruction: lane group g=lane>>4
//      loads float4 (features (lane&15)*4..+3) of edge 4t+g. Serial depth
//      drops 4x (~4-5 iterations), shfl count drops 4x; shfl_xor(16/32)
//      reduce recombines the 4 group partials.
//  (b) CSR scan pipeline replaced by fixed-capacity buckets
//      (eid[node*48+slot], slot=atomicAdd(cnt)). memset(800KB) + ONE build
//      kernel instead of 6 dispatches. Overflow (deg>48, never happens for
//      Poisson(8) degrees) goes to a device list handled by a cold predicated
//      path in the fused kernel.

#define NB 32            // nodes per block in fused kernel (100000 % 32 == 0)
#define CAP 48           // edge bucket capacity per node per chain
#define OVF_MAX 65536    // overflow list capacity (entries)

// ---------------------------------------------------------------------------
// 1) Build buckets: slot = cnt[recv]++; eid[recv*CAP+slot] = e.
// ---------------------------------------------------------------------------
__global__ __launch_bounds__(256) void build_kernel(
    const int* __restrict__ ra, const int* __restrict__ rb,
    int* __restrict__ cnt_a, int* __restrict__ cnt_b,
    int* __restrict__ eid_a, int* __restrict__ eid_b,
    int* __restrict__ ovf_cnt, int2* __restrict__ ovf, int n_edges) {
  const int e = blockIdx.x * 256 + threadIdx.x;
  if (e >= n_edges) return;
  {
    const int r = ra[e];
    const int s = atomicAdd(&cnt_a[r], 1);
    if (s < CAP) {
      eid_a[r * CAP + s] = e;
    } else {
      const int k = atomicAdd(ovf_cnt, 1);
      if (k < OVF_MAX) ovf[k] = make_int2(r, e);  // chain a: bit30 clear
    }
  }
  {
    const int r = rb[e];
    const int s = atomicAdd(&cnt_b[r], 1);
    if (s < CAP) {
      eid_b[r * CAP + s] = e;
    } else {
      const int k = atomicAdd(ovf_cnt, 1);
      if (k < OVF_MAX) ovf[k] = make_int2(r | 0x40000000, e);  // chain b
    }
  }
}

// ---------------------------------------------------------------------------
// 2) Fused gather + concat + GEMM + bias.
//    Gather per wave (8 nodes): lane-parallel eid prefetch (lane t = slot t),
//    then ceil(maxdeg/4) iterations; per iteration each of the 4 lane groups
//    loads float4 of its edge (4t+g) for all 8 nodes x {a,b} = 16 independent
//    loads. shfl_xor(16/32) group-reduce, write xs, then fp32 GEMM.
// ---------------------------------------------------------------------------
__device__ __forceinline__ void fma4(float4& acc, float s, const float4& w) {
  acc.x = fmaf(s, w.x, acc.x);
  acc.y = fmaf(s, w.y, acc.y);
  acc.z = fmaf(s, w.z, acc.z);
  acc.w = fmaf(s, w.w, acc.w);
}

__device__ __forceinline__ void macc4(float4& acc, float m, const float4& v) {
  acc.x = fmaf(m, v.x, acc.x);
  acc.y = fmaf(m, v.y, acc.y);
  acc.z = fmaf(m, v.z, acc.z);
  acc.w = fmaf(m, v.w, acc.w);
}

__global__ __launch_bounds__(256) void fused_gather_gemm(
    const float* __restrict__ edata_a, const float* __restrict__ edata_b,
    const int* __restrict__ eid_a, const int* __restrict__ eid_b,
    const int* __restrict__ cnt_a, const int* __restrict__ cnt_b,
    const int* __restrict__ ovf_cnt, const int2* __restrict__ ovf,
    const float* __restrict__ vdata, const float* __restrict__ W,
    const float* __restrict__ bias, float* __restrict__ out, int n_nodes) {
  __shared__ float xs[NB][260];

  const int tid = threadIdx.x;
  const int lane = tid & 63;
  const int wv = tid >> 6;   // wave 0..3
  const int n0 = blockIdx.x * NB;
  const int ln0 = wv * 8;    // this wave's first local node

  // ---- metadata: lane&7 -> node j; clamp to CAP; hoist to SGPRs ----
  const int nj = n0 + ln0 + (lane & 7);
  int ca = 0, cb = 0;
  if (nj < n_nodes) { ca = cnt_a[nj]; cb = cnt_b[nj]; }
  ca = ca < CAP ? ca : CAP;
  cb = cb < CAP ? cb : CAP;

  int caj[8], cbj[8];
#pragma unroll
  for (int j = 0; j < 8; ++j) {
    caj[j] = __builtin_amdgcn_readlane(ca, j);
    cbj[j] = __builtin_amdgcn_readlane(cb, j);
  }

  // ---- eid prefetch: lane t holds slot t of node j (t < CAP) ----
  int eA[8], eB[8];
#pragma unroll
  for (int j = 0; j < 8; ++j) {
    const int n = n0 + ln0 + j;
    eA[j] = (lane < caj[j]) ? eid_a[(size_t)n * CAP + lane] : 0;
    eB[j] = (lane < cbj[j]) ? eid_b[(size_t)n * CAP + lane] : 0;
  }

  // ---- stage vdata into cols 128..255 (independent VMEM; fills latency) ----
  const float4* V4 = (const float4*)(vdata + (size_t)n0 * 128);
#pragma unroll
  for (int i = tid; i < NB * 32; i += 256) {
    const int node = i >> 5;
    const int kk = (i & 31) << 2;
    *(float4*)&xs[node][128 + kk] = V4[i];
  }

  // ---- group-parallel accumulation ----
  const int g = lane >> 4;          // edge subgroup 0..3
  const int fo = (lane & 15) << 2;  // feature offset 0..60
  float4 aa[8], ab[8];
#pragma unroll
  for (int j = 0; j < 8; ++j) {
    aa[j] = make_float4(0.f, 0.f, 0.f, 0.f);
    ab[j] = make_float4(0.f, 0.f, 0.f, 0.f);
  }

  int mdeg = 0;
#pragma unroll
  for (int j = 0; j < 8; ++j) {
    const int m = caj[j] > cbj[j] ? caj[j] : cbj[j];
    mdeg = mdeg > m ? mdeg : m;
  }
  const int iters = (mdeg + 3) >> 2;

  for (int t = 0; t < iters; ++t) {
    const int idx = (t << 2) + g;   // this lane group's edge slot
#pragma unroll
    for (int j = 0; j < 8; ++j) {
      const int ida = __shfl(eA[j], idx);   // 0 when idx >= caj -> safe addr
      const int idb = __shfl(eB[j], idx);
      const float4 va = *(const float4*)&edata_a[(size_t)ida * 64 + fo];
      const float4 vb = *(const float4*)&edata_b[(size_t)idb * 64 + fo];
      const float ma = idx < caj[j] ? 1.f : 0.f;
      const float mb = idx < cbj[j] ? 1.f : 0.f;
      macc4(aa[j], ma, va);
      macc4(ab[j], mb, vb);
    }
  }

  // ---- reduce the 4 lane-group partials (xor 16, then 32) ----
#pragma unroll
  for (int j = 0; j < 8; ++j) {
    aa[j].x += __shfl_xor(aa[j].x, 16); aa[j].y += __shfl_xor(aa[j].y, 16);
    aa[j].z += __shfl_xor(aa[j].z, 16); aa[j].w += __shfl_xor(aa[j].w, 16);
    aa[j].x += __shfl_xor(aa[j].x, 32); aa[j].y += __shfl_xor(aa[j].y, 32);
    aa[j].z += __shfl_xor(aa[j].z, 32); aa[j].w += __shfl_xor(aa[j].w, 32);
    ab[j].x += __shfl_xor(ab[j].x, 16); ab[j].y += __shfl_xor(ab[j].y, 16);
    ab[j].z += __shfl_xor(ab[j].z, 16); ab[j].w += __shfl_xor(ab[j].w, 16);
    ab[j].x += __shfl_xor(ab[j].x, 32); ab[j].y += __shfl_xor(ab[j].y, 32);
    ab[j].z += __shfl_xor(ab[j].z, 32); ab[j].w += __shfl_xor(ab[j].w, 32);
  }

  // ---- overflow (deg > CAP): cold path, static-indexed predicated adds ----
  {
    int novf = *ovf_cnt;
    novf = novf < OVF_MAX ? novf : OVF_MAX;
    if (novf > 0) {
      for (int k = 0; k < novf; ++k) {
        const int2 o = ovf[k];
        const int node = o.x & 0x3FFFFFFF;
        const int chain = (o.x >> 30) & 1;
        const int lj = node - (n0 + ln0);
        if (0 <= lj && lj < 8) {
          const float4 v = chain == 0
              ? *(const float4*)&edata_a[(size_t)o.y * 64 + fo]
              : *(const float4*)&edata_b[(size_t)o.y * 64 + fo];
#pragma unroll
          for (int j = 0; j < 8; ++j) {
            if (j == lj) {
              if (chain == 0) { aa[j].x += v.x; aa[j].y += v.y; aa[j].z += v.z; aa[j].w += v.w; }
              else            { ab[j].x += v.x; ab[j].y += v.y; ab[j].z += v.z; ab[j].w += v.w; }
            }
          }
        }
      }
    }
  }

  // ---- write agg rows (all lanes hold full sums; 16 lanes suffice) ----
  if (lane < 16) {
#pragma unroll
    for (int j = 0; j < 8; ++j) {
      *(float4*)&xs[ln0 + j][fo] = aa[j];
      *(float4*)&xs[ln0 + j][64 + fo] = ab[j];
    }
  }
  __syncthreads();

  // ---- GEMM: thread t -> cols 4*(t&31)..+3, nodes (t>>5)*4..+3 ----
  const int c = tid & 31;
  const int nset = tid >> 5;
  const float4* W4 = (const float4*)W;

  float4 acc0 = {0.f, 0.f, 0.f, 0.f};
  float4 acc1 = acc0, acc2 = acc0, acc3 = acc0;

#pragma unroll 4
  for (int k = 0; k < 256; k += 4) {
    const float4 w0 = W4[(k + 0) * 32 + c];
    const float4 w1 = W4[(k + 1) * 32 + c];
    const float4 w2 = W4[(k + 2) * 32 + c];
    const float4 w3 = W4[(k + 3) * 32 + c];
    const float4 x0 = *(const float4*)&xs[nset * 4 + 0][k];
    const float4 x1 = *(const float4*)&xs[nset * 4 + 1][k];
    const float4 x2 = *(const float4*)&xs[nset * 4 + 2][k];
    const float4 x3 = *(const float4*)&xs[nset * 4 + 3][k];

    fma4(acc0, x0.x, w0); fma4(acc0, x0.y, w1); fma4(acc0, x0.z, w2); fma4(acc0, x0.w, w3);
    fma4(acc1, x1.x, w0); fma4(acc1, x1.y, w1); fma4(acc1, x1.z, w2); fma4(acc1, x1.w, w3);
    fma4(acc2, x2.x, w0); fma4(acc2, x2.y, w1); fma4(acc2, x2.z, w2); fma4(acc2, x2.w, w3);
    fma4(acc3, x3.x, w0); fma4(acc3, x3.y, w1); fma4(acc3, x3.z, w2); fma4(acc3, x3.w, w3);
  }

  // ---- epilogue: bias + store ----
  const float4 bb = ((const float4*)bias)[c];
  acc0.x += bb.x; acc0.y += bb.y; acc0.z += bb.z; acc0.w += bb.w;
  acc1.x += bb.x; acc1.y += bb.y; acc1.z += bb.z; acc1.w += bb.w;
  acc2.x += bb.x; acc2.y += bb.y; acc2.z += bb.z; acc2.w += bb.w;
  acc3.x += bb.x; acc3.y += bb.y; acc3.z += bb.z; acc3.w += bb.w;

  float4* O4 = (float4*)out;
  const int nb = n0 + nset * 4;
  if (nb + 3 < n_nodes) {
    O4[(size_t)(nb + 0) * 32 + c] = acc0;
    O4[(size_t)(nb + 1) * 32 + c] = acc1;
    O4[(size_t)(nb + 2) * 32 + c] = acc2;
    O4[(size_t)(nb + 3) * 32 + c] = acc3;
  } else {
    if (nb + 0 < n_nodes) O4[(size_t)(nb + 0) * 32 + c] = acc0;
    if (nb + 1 < n_nodes) O4[(size_t)(nb + 1) * 32 + c] = acc1;
    if (nb + 2 < n_nodes) O4[(size_t)(nb + 2) * 32 + c] = acc2;
    if (nb + 3 < n_nodes) O4[(size_t)(nb + 3) * 32 + c] = acc3;
  }
}

// ---------------------------------------------------------------------------
// Launch
// ---------------------------------------------------------------------------
extern "C" void kernel_launch(void* const* d_in, const int* in_sizes, int n_in,
                              void* d_out, int out_size, void* d_ws, size_t ws_size,
                              hipStream_t stream) {
  const float* vdata   = (const float*)d_in[0];
  const float* edata_a = (const float*)d_in[1];
  const float* edata_b = (const float*)d_in[2];
  const int*   conn_a  = (const int*)d_in[3];  // [2, E] int32
  const int*   conn_b  = (const int*)d_in[4];
  const float* W       = (const float*)d_in[5];
  const float* bias    = (const float*)d_in[6];
  float*       out     = (float*)d_out;

  const int n_nodes = in_sizes[0] / 128;  // 100000
  const int n_edges = in_sizes[1] / 64;   // 800000

  const int* recv_a = conn_a + n_edges;   // row 1 = receivers
  const int* recv_b = conn_b + n_edges;

  // Workspace layout (ints): [cnt_a | cnt_b | ovf_cnt(+pad 8) | ovf(2*OVF_MAX)
  //                           | eid_a(n*CAP) | eid_b(n*CAP)]  ~= 39.7 MB
  int* cnt_a   = (int*)d_ws;
  int* cnt_b   = cnt_a + n_nodes;
  int* ovf_cnt = cnt_b + n_nodes;                 // 8 ints (pad for alignment)
  int2* ovf    = (int2*)(ovf_cnt + 8);            // 8B-aligned
  int* eid_a   = (int*)(ovf + OVF_MAX);
  int* eid_b   = eid_a + (size_t)n_nodes * CAP;

  // zero counters + overflow counter only
  hipMemsetAsync(d_ws, 0, ((size_t)2 * n_nodes + 8) * sizeof(int), stream);

  const int eblocks = (n_edges + 255) / 256;  // 3125
  build_kernel<<<eblocks, 256, 0, stream>>>(recv_a, recv_b, cnt_a, cnt_b,
                                            eid_a, eid_b, ovf_cnt, ovf, n_edges);

  const int gblocks = (n_nodes + NB - 1) / NB;  // 3125
  fused_gather_gemm<<<gblocks, 256, 0, stream>>>(
      edata_a, edata_b, eid_a, eid_b, cnt_a, cnt_b, ovf_cnt, ovf,
      vdata, W, bias, out, n_nodes);
}